// Round 9
// baseline (434.151 us; speedup 1.0000x reference)
//
#include <hip/hip_runtime.h>

typedef __bf16 bf16x8 __attribute__((ext_vector_type(8)));
typedef __bf16 bf16x4 __attribute__((ext_vector_type(4)));
typedef float  f32x4  __attribute__((ext_vector_type(4)));

__device__ __forceinline__ void g2l16(const void* g, void* l) {
    __builtin_amdgcn_global_load_lds((const __attribute__((address_space(1))) void*)g,
                                     (__attribute__((address_space(3))) void*)l, 16, 0, 0);
}

// Shared NT K-loop core. Tile = (MCH*32) x (NCH*32), 4 waves 2x2.
// LDS: unpadded [rows][64] bf16, 16B-unit XOR swizzle (unit ^= row&7) at the
// global SOURCE column + fragment reads -> 0 bank conflicts (R2/R4/R5).
template<int MCH, int NCH>
__device__ __forceinline__ void gemm_core(
    const __bf16* __restrict__ At, const __bf16* __restrict__ Bt,
    int lda, int ldb, int K,
    __bf16* As, __bf16* Bs, f32x4 (&acc)[MCH][NCH], int tid)
{
    const int w = tid >> 6, lane = tid & 63;
    const int quad = lane >> 4, l16 = lane & 15;
    const int wm = w & 1, wn = w >> 1;

    const int srow = (w << 3) + (lane >> 3);
    const int scol = ((lane & 7) ^ (lane >> 3)) << 3;
    char* ldsA = (char*)As + (size_t)w * 1024;
    char* ldsB = (char*)Bs + (size_t)w * 1024;
    const __bf16* Ag = At + (size_t)srow * lda + scol;
    const __bf16* Bg = Bt + (size_t)srow * ldb + scol;

    for (int k0 = 0; k0 < K; k0 += 64) {
        __syncthreads();
        #pragma unroll
        for (int c = 0; c < MCH; c++)
            g2l16(Ag + (size_t)(c * 32) * lda + k0, ldsA + c * 4096);
        #pragma unroll
        for (int c = 0; c < NCH; c++)
            g2l16(Bg + (size_t)(c * 32) * ldb + k0, ldsB + c * 4096);
        __syncthreads();

        #pragma unroll
        for (int kk = 0; kk < 64; kk += 32) {
            const int ub = kk >> 3;
            bf16x8 a[MCH], b[NCH];
            #pragma unroll
            for (int mt = 0; mt < MCH; mt++) {
                const int row = wm * (MCH * 16) + mt * 16 + l16;
                a[mt] = *(const bf16x8*)&As[row * 64 + (((quad + ub) ^ (row & 7)) << 3)];
            }
            #pragma unroll
            for (int nt = 0; nt < NCH; nt++) {
                const int row = wn * (NCH * 16) + nt * 16 + l16;
                b[nt] = *(const bf16x8*)&Bs[row * 64 + (((quad + ub) ^ (row & 7)) << 3)];
            }
            #pragma unroll
            for (int mt = 0; mt < MCH; mt++)
                #pragma unroll
                for (int nt = 0; nt < NCH; nt++)
                    acc[mt][nt] = __builtin_amdgcn_mfma_f32_16x16x32_bf16(
                        a[mt], b[nt], acc[mt][nt], 0, 0, 0);
        }
    }
}

// ---------------- Phase device functions (R5-proven logic) ----------------

__device__ __forceinline__ void cvt_piece(
    int i, const float* x, const float* Wq, const float* Wk, const float* Wv,
    __bf16* xb, __bf16* Wqb)
{
    const float* s; __bf16* d; int off;
    if (i < 1048576)      { s = x;  d = xb;            off = i; }
    else if (i < 1056768) { s = Wq; d = Wqb;           off = i - 1048576; }
    else if (i < 1064960) { s = Wk; d = Wqb + 131072;  off = i - 1056768; }
    else                  { s = Wv; d = Wqb + 262144;  off = i - 1064960; }
    const float4 f0 = ((const float4*)s)[off * 2];
    const float4 f1 = ((const float4*)s)[off * 2 + 1];
    bf16x8 o;
    o[0] = (__bf16)f0.x; o[1] = (__bf16)f0.y; o[2] = (__bf16)f0.z; o[3] = (__bf16)f0.w;
    o[4] = (__bf16)f1.x; o[5] = (__bf16)f1.y; o[6] = (__bf16)f1.z; o[7] = (__bf16)f1.w;
    ((bf16x8*)d)[off] = o;
}

// Projection tile t in [0,3072): 128x64. z<2 row-major q/k; z==2 transposed vT.
__device__ __forceinline__ void proj_tile(
    int t, const __bf16* xb, const __bf16* Wqb, const float* bpack,
    __bf16* qkv, __bf16* vT, __bf16* As, __bf16* Bs, int tid)
{
    const int z = t >> 10, lc = t & 1023;
    const int m0 = (lc & 255) * 128;
    const int n0 = (lc >> 8) * 64;
    f32x4 acc[4][2] = {};
    gemm_core<4, 2>(xb + (size_t)m0 * 256, Wqb + z * 131072 + n0 * 256,
                    256, 256, 256, As, Bs, acc, tid);
    const int w = tid >> 6, lane = tid & 63, quad = lane >> 4, l16 = lane & 15;
    const int wm = w & 1, wn = w >> 1;
    #pragma unroll
    for (int mt = 0; mt < 4; mt++) {
        const int mb = m0 + wm * 64 + mt * 16 + quad * 4;
        #pragma unroll
        for (int nt = 0; nt < 2; nt++) {
            const int n = n0 + wn * 32 + nt * 16 + l16;
            if (z < 2) {
                const float bn = bpack[z * 256 + n];
                __bf16* C = qkv + (size_t)z * 8388608;
                #pragma unroll
                for (int r = 0; r < 4; r++)
                    C[(size_t)(mb + r) * 256 + n] = (__bf16)(acc[mt][nt][r] + bn);
            } else {
                const float bn = bpack[512 + n];
                bf16x4 pk;
                #pragma unroll
                for (int r = 0; r < 4; r++) pk[r] = (__bf16)(acc[mt][nt][r] + bn);
                *(bf16x4*)(vT + (size_t)(mb >> 10) * 262144
                           + (size_t)n * 1024 + (mb & 1023)) = pk;
            }
        }
    }
}

// Logits tile id in [0,2048): 128x128. XCD-sequential (R5: FETCH 74->12.5MB).
__device__ __forceinline__ void logits_tile(
    int id, const __bf16* qkv, __bf16* E, __bf16* As, __bf16* Bs, int tid)
{
    const int x8 = id & 7, s = id >> 3;
    const int z  = x8 + ((s >> 6) << 3);
    const int t  = s & 63;
    const int m0 = (t & 7) * 128;
    const int n0 = (t >> 3) * 128;
    f32x4 acc[4][4] = {};
    gemm_core<4, 4>(qkv + (size_t)z * 262144 + m0 * 256,
                    qkv + 8388608 + (size_t)z * 262144 + n0 * 256,
                    256, 256, 256, As, Bs, acc, tid);
    const int w = tid >> 6, lane = tid & 63, quad = lane >> 4, l16 = lane & 15;
    const int wm = w & 1, wn = w >> 1;
    __bf16* Eb = E + (size_t)z * 1048576;
    #pragma unroll
    for (int mt = 0; mt < 4; mt++) {
        const int mb = m0 + wm * 64 + mt * 16 + quad * 4;
        #pragma unroll
        for (int nt = 0; nt < 4; nt++) {
            const int n = n0 + wn * 64 + nt * 16 + l16;
            #pragma unroll
            for (int r = 0; r < 4; r++)
                Eb[(size_t)(mb + r) * 1024 + n] = (__bf16)__expf(acc[mt][nt][r]);
        }
    }
}

// Softmax over batch axis at bf16x4 grain, p in [0,262144).
__device__ __forceinline__ void softmax_unit(int p, __bf16* E)
{
    bf16x4* E4 = (bf16x4*)E;
    bf16x4 e[32];
    #pragma unroll
    for (int b = 0; b < 32; b++) e[b] = E4[(size_t)b * 262144 + p];
    float sm[4] = {0.f, 0.f, 0.f, 0.f};
    #pragma unroll
    for (int b = 0; b < 32; b++)
        #pragma unroll
        for (int j = 0; j < 4; j++) sm[j] += (float)e[b][j];
    float rs[4];
    #pragma unroll
    for (int j = 0; j < 4; j++) rs[j] = __builtin_amdgcn_rcpf(sm[j]);
    #pragma unroll
    for (int b = 0; b < 32; b++) {
        bf16x4 o;
        #pragma unroll
        for (int j = 0; j < 4; j++) o[j] = (__bf16)((float)e[b][j] * rs[j]);
        E4[(size_t)b * 262144 + p] = o;
    }
}

// PV tile id in [0,1024): 128x64, out fp32 row-major. XCD-sequential.
__device__ __forceinline__ void pv_tile(
    int id, const __bf16* E, const __bf16* vT, float* out,
    __bf16* As, __bf16* Bs, int tid)
{
    const int x8 = id & 7, s = id >> 3;
    const int z  = x8 + ((s >> 5) << 3);
    const int t  = s & 31;
    const int m0 = (t & 7) * 128;
    const int n0 = (t >> 3) * 64;
    f32x4 acc[4][2] = {};
    gemm_core<4, 2>(E + (size_t)z * 1048576 + (size_t)m0 * 1024,
                    vT + (size_t)z * 262144 + (size_t)n0 * 1024,
                    1024, 1024, 1024, As, Bs, acc, tid);
    const int w = tid >> 6, lane = tid & 63, quad = lane >> 4, l16 = lane & 15;
    const int wm = w & 1, wn = w >> 1;
    float* Ob = out + (size_t)z * 262144;
    #pragma unroll
    for (int mt = 0; mt < 4; mt++) {
        const int mb = m0 + wm * 64 + mt * 16 + quad * 4;
        #pragma unroll
        for (int nt = 0; nt < 2; nt++) {
            const int n = n0 + wn * 32 + nt * 16 + l16;
            #pragma unroll
            for (int r = 0; r < 4; r++)
                Ob[(size_t)(mb + r) * 256 + n] = acc[mt][nt][r];
        }
    }
}

// Device-scope grid barrier (monotonic counter, zeroed by hipMemsetAsync
// before launch). Release fence -> agent atomicAdd -> spin -> acquire fence.
// Correct under per-XCD L2 non-coherence: __threadfence() at agent scope
// emits L2 writeback (release) / invalidate (acquire) on gfx950; the block's
// own stores are drained by the s_waitcnt vmcnt(0) __syncthreads implies.
__device__ __forceinline__ void gbar(unsigned int* ctr, unsigned int target)
{
    __syncthreads();
    if (threadIdx.x == 0) {
        __threadfence();
        __hip_atomic_fetch_add(ctr, 1u, __ATOMIC_RELAXED, __HIP_MEMORY_SCOPE_AGENT);
        while (__hip_atomic_load(ctr, __ATOMIC_RELAXED, __HIP_MEMORY_SCOPE_AGENT)
               < target)
            __builtin_amdgcn_s_sleep(8);
        __threadfence();
    }
    __syncthreads();
}

// Persistent mega-kernel: grid 512, __launch_bounds__(256,2) guarantees
// >=2 blocks/CU co-resident (512 = exactly 2x256CU) -> barrier cannot
// deadlock. Plain launch -> graph-capture-safe (cooperative API is not).
__global__ __launch_bounds__(256, 2)
void mega(const float* __restrict__ x,  const float* __restrict__ Wq,
          const float* __restrict__ bq, const float* __restrict__ Wk,
          const float* __restrict__ bk, const float* __restrict__ Wv,
          const float* __restrict__ bv,
          __bf16* __restrict__ xb,  __bf16* __restrict__ qkv,
          __bf16* __restrict__ vT,  __bf16* __restrict__ E,
          __bf16* __restrict__ Wqb, float* __restrict__ bpack,
          unsigned int* __restrict__ bar, float* __restrict__ out)
{
    __shared__ __align__(16) __bf16 As[128 * 64];
    __shared__ __align__(16) __bf16 Bs[128 * 64];
    const int tid = threadIdx.x, blk = blockIdx.x;

    // Phase 1: fp32->bf16 converts + bias pack
    {
        const int g0 = blk * 256 + tid;
        for (int i = g0; i < 1073152; i += 131072)
            cvt_piece(i, x, Wq, Wk, Wv, xb, Wqb);
        if (g0 < 192) {
            const int sel = g0 >> 6, jj = g0 & 63;
            const float* s = sel == 0 ? bq : (sel == 1 ? bk : bv);
            ((float4*)bpack)[g0] = ((const float4*)s)[jj];
        }
    }
    gbar(bar, 512);

    // Phase 2: projections (3072 tiles of 128x64)
    for (int it = 0; it < 6; it++)
        proj_tile(blk + it * 512, xb, Wqb, bpack, qkv, vT, As, Bs, tid);
    gbar(bar, 1024);

    // Phase 3: logits (2048 tiles of 128x128, XCD-sequential)
    for (int it = 0; it < 4; it++)
        logits_tile(blk + it * 512, qkv, E, As, Bs, tid);
    gbar(bar, 1536);

    // Phase 4: batch-axis softmax (262144 bf16x4 units)
    for (int it = 0; it < 2; it++)
        softmax_unit(blk * 256 + tid + it * 131072, E);
    gbar(bar, 2048);

    // Phase 5: PV (1024 tiles of 128x64)
    for (int it = 0; it < 2; it++)
        pv_tile(blk + it * 512, E, vT, out, As, Bs, tid);
}

extern "C" void kernel_launch(void* const* d_in, const int* in_sizes, int n_in,
                              void* d_out, int out_size, void* d_ws, size_t ws_size,
                              hipStream_t stream)
{
    const float* x  = (const float*)d_in[0];
    const float* Wq = (const float*)d_in[1];
    const float* bq = (const float*)d_in[2];
    const float* Wk = (const float*)d_in[3];
    const float* bk = (const float*)d_in[4];
    const float* Wv = (const float*)d_in[5];
    const float* bv = (const float*)d_in[6];
    float* out = (float*)d_out;

    // Workspace: [0,16M) xb | [16M,32M) q | [32M,48M) k | [48M,64M) vT
    //            [64M,128M) E | [128M,+768K) Wqkv bf16 | +768K bpack fp32[768]
    //            +772K barrier counter (zeroed each call)
    char* ws = (char*)d_ws;
    __bf16* xb    = (__bf16*)(ws);
    __bf16* qkv   = (__bf16*)(ws + (16u << 20));
    __bf16* vT    = (__bf16*)(ws + (48u << 20));
    __bf16* E     = (__bf16*)(ws + (64u << 20));
    __bf16* Wqb   = (__bf16*)(ws + (128u << 20));
    float*  bpack = (float*) (ws + (128u << 20) + (3u << 18));
    unsigned int* bar = (unsigned int*)(ws + (128u << 20) + (3u << 18) + 4096);

    hipMemsetAsync(bar, 0, 256, stream);
    mega<<<512, 256, 0, stream>>>(x, Wq, bq, Wk, bk, Wv, bv,
                                  xb, qkv, vT, E, Wqb, bpack, bar, out);
}

// Round 10
// 254.108 us; speedup vs baseline: 1.7085x; 1.7085x over previous
//
#include <hip/hip_runtime.h>

typedef __bf16 bf16x8 __attribute__((ext_vector_type(8)));
typedef __bf16 bf16x4 __attribute__((ext_vector_type(4)));
typedef float  f32x4  __attribute__((ext_vector_type(4)));

#define BM 128
#define BN 128
#define BK 64

__device__ __forceinline__ void g2l16(const void* g, void* l) {
    __builtin_amdgcn_global_load_lds((const __attribute__((address_space(1))) void*)g,
                                     (__attribute__((address_space(3))) void*)l, 16, 0, 0);
}

// NT GEMM (R5-verified): 128x128 tile, BK=64, 4 waves 2x2.
// LDS: unpadded [128][64] bf16, 16B-unit XOR swizzle (unit ^= row&7) at the
// global SOURCE column + fragment reads -> 0 bank conflicts.
// EPI: 2 = exp -> bf16 row-major store [logits -> E]
//      4 = +bias projection; z<2 bf16 row-major (q,k), z==2 transposed vT
// SWZ: 1 = XCD-sequential flat grid (logits): FETCH 74->12.5MB verified R5.
template<int EPI, int SWZ>
__global__ __launch_bounds__(256)
void gemm_nt(const __bf16* __restrict__ A, const __bf16* __restrict__ B,
             void* __restrict__ Cv, const float* __restrict__ bias,
             int lda, int ldb, int ldc, int K,
             long sA, long sB, long sC)
{
    __shared__ __align__(16) __bf16 As[BM * BK];
    __shared__ __align__(16) __bf16 Bs[BN * BK];

    const int tid  = threadIdx.x;
    const int w    = tid >> 6;
    const int lane = tid & 63;
    const int quad = lane >> 4;
    const int l16  = lane & 15;
    const int wm   = w & 1;
    const int wn   = w >> 1;

    int m0, n0, z;
    if constexpr (SWZ == 1) {
        const int id = blockIdx.x;
        const int x  = id & 7, s = id >> 3;
        z = x + ((s >> 6) << 3);
        const int t = s & 63;
        m0 = (t & 7) * BM;
        n0 = (t >> 3) * BN;
    } else {
        m0 = blockIdx.x * BM;
        n0 = blockIdx.y * BN;
        z  = blockIdx.z;
    }

    const __bf16* Ab = A + (size_t)z * sA;
    const __bf16* Bb = B + (size_t)z * sB;

    const int srow = (w << 3) + (lane >> 3);
    const int scol = ((lane & 7) ^ (lane >> 3)) << 3;
    char* ldsA = (char*)As + (size_t)w * 1024;
    char* ldsB = (char*)Bs + (size_t)w * 1024;

    const __bf16* Ag = Ab + (size_t)(m0 + srow) * lda + scol;
    const __bf16* Bg = Bb + (size_t)(n0 + srow) * ldb + scol;

    f32x4 acc[4][4] = {};

    for (int k0 = 0; k0 < K; k0 += BK) {
        __syncthreads();
        #pragma unroll
        for (int c = 0; c < 4; c++)
            g2l16(Ag + (size_t)(c * 32) * lda + k0, ldsA + c * 4096);
        #pragma unroll
        for (int c = 0; c < 4; c++)
            g2l16(Bg + (size_t)(c * 32) * ldb + k0, ldsB + c * 4096);
        __syncthreads();

        #pragma unroll
        for (int kk = 0; kk < BK; kk += 32) {
            const int ub = kk >> 3;
            bf16x8 a[4], b[4];
            #pragma unroll
            for (int mt = 0; mt < 4; mt++) {
                const int row = wm * 64 + mt * 16 + l16;
                a[mt] = *(const bf16x8*)&As[row * BK + (((quad + ub) ^ (row & 7)) << 3)];
            }
            #pragma unroll
            for (int nt = 0; nt < 4; nt++) {
                const int row = wn * 64 + nt * 16 + l16;
                b[nt] = *(const bf16x8*)&Bs[row * BK + (((quad + ub) ^ (row & 7)) << 3)];
            }
            #pragma unroll
            for (int mt = 0; mt < 4; mt++)
                #pragma unroll
                for (int nt = 0; nt < 4; nt++)
                    acc[mt][nt] = __builtin_amdgcn_mfma_f32_16x16x32_bf16(
                        a[mt], b[nt], acc[mt][nt], 0, 0, 0);
        }
    }

    // Epilogue. C/D layout (m89/m91): row = quad*4 + reg, col = l16.
    #pragma unroll
    for (int mt = 0; mt < 4; mt++) {
        const int mb = m0 + wm * 64 + mt * 16 + quad * 4;
        #pragma unroll
        for (int nt = 0; nt < 4; nt++) {
            const int n = n0 + wn * 64 + nt * 16 + l16;
            if constexpr (EPI == 2) {
                __bf16* C = (__bf16*)Cv + (size_t)z * sC;
                #pragma unroll
                for (int r = 0; r < 4; r++)
                    C[(size_t)(mb + r) * ldc + n] = (__bf16)__expf(acc[mt][nt][r]);
            } else {  // EPI == 4
                const float bn = bias[z * 256 + n];
                if (z < 2) {
                    __bf16* C = (__bf16*)Cv + (size_t)z * sC;
                    #pragma unroll
                    for (int r = 0; r < 4; r++)
                        C[(size_t)(mb + r) * ldc + n] = (__bf16)(acc[mt][nt][r] + bn);
                } else {
                    // vT[b][d=n][m]: batch stride 262144, d stride 1024
                    __bf16* C = (__bf16*)Cv + 2 * sC;
                    const int bidx = mb >> 10, mloc = mb & 1023;
                    bf16x4 pk;
                    #pragma unroll
                    for (int r = 0; r < 4; r++) pk[r] = (__bf16)(acc[mt][nt][r] + bn);
                    *(bf16x4*)(C + (size_t)bidx * 262144 + (size_t)n * 1024 + mloc) = pk;
                }
            }
        }
    }
}

// PV with fused batch-softmax normalization. R5 geometry (128n x 64d tiles,
// grid 1024 = 4 blocks/CU, XCD-sequential) + R4's verified normalize-during-
// A-staging (load E bf16x8, scale by fp32 Srcp, swizzled ds_write_b128;
// R4 measured 0 bank conflicts). B (vT) stays on global_load_lds.
__global__ __launch_bounds__(256)
void gemm_pv(const __bf16* __restrict__ E, const float* __restrict__ Srcp,
             const __bf16* __restrict__ vT, float* __restrict__ out)
{
    __shared__ __align__(16) __bf16 As[128 * 64];   // 16 KB
    __shared__ __align__(16) __bf16 Bs[64 * 64];    //  8 KB

    const int tid  = threadIdx.x;
    const int w    = tid >> 6;
    const int lane = tid & 63;
    const int quad = lane >> 4;
    const int l16  = lane & 15;
    const int wm   = w & 1;        // 64-row half (n)
    const int wn   = w >> 1;       // 32-col half (d)

    const int id = blockIdx.x;
    const int x  = id & 7, s = id >> 3;        // s: 0..127
    const int z  = x + ((s >> 5) << 3);        // 4 batches per XCD, sequential
    const int t  = s & 31;
    const int m0 = (t & 7) * 128;              // n-row tile
    const int n0 = (t >> 3) * 64;              // d-col tile

    const __bf16* Eb = E  + (size_t)z * 1048576;
    const __bf16* Vb = vT + (size_t)z * 262144;
    float*        Ob = out + (size_t)z * 262144;

    // B staging (global_load_lds, swizzled source col), 2 chunks of 32 rows
    const int srow = (w << 3) + (lane >> 3);
    const int scol = ((lane & 7) ^ (lane >> 3)) << 3;
    char* ldsB = (char*)Bs + (size_t)w * 1024;
    const __bf16* Bg = Vb + (size_t)(n0 + srow) * 1024 + scol;

    // A staging (VGPR roundtrip + normalize): thread owns row = tid>>1,
    // 8-col units (tid&1)*4 + s4, s4=0..3.
    const int arow = tid >> 1;
    const int auh  = (tid & 1) * 4;
    const __bf16* Ag = Eb + (size_t)(m0 + arow) * 1024;
    const float*  Sg = Srcp + (size_t)(m0 + arow) * 1024;
    __bf16* Ad = As + arow * 64;

    f32x4 acc[4][2] = {};

    for (int k0 = 0; k0 < 1024; k0 += BK) {
        __syncthreads();
        #pragma unroll
        for (int c = 0; c < 2; c++)
            g2l16(Bg + (size_t)(c * 32) * 1024 + k0, ldsB + c * 4096);
        #pragma unroll
        for (int s4 = 0; s4 < 4; s4++) {
            const int u   = auh + s4;
            const int col = k0 + u * 8;
            bf16x8 e  = *(const bf16x8*)(Ag + col);
            f32x4  r0 = *(const f32x4*)(Sg + col);
            f32x4  r1 = *(const f32x4*)(Sg + col + 4);
            bf16x8 en;
            en[0] = (__bf16)((float)e[0] * r0[0]);
            en[1] = (__bf16)((float)e[1] * r0[1]);
            en[2] = (__bf16)((float)e[2] * r0[2]);
            en[3] = (__bf16)((float)e[3] * r0[3]);
            en[4] = (__bf16)((float)e[4] * r1[0]);
            en[5] = (__bf16)((float)e[5] * r1[1]);
            en[6] = (__bf16)((float)e[6] * r1[2]);
            en[7] = (__bf16)((float)e[7] * r1[3]);
            *(bf16x8*)(Ad + ((u ^ (arow & 7)) << 3)) = en;
        }
        __syncthreads();

        #pragma unroll
        for (int kk = 0; kk < BK; kk += 32) {
            const int ub = kk >> 3;
            bf16x8 a[4], b[2];
            #pragma unroll
            for (int mt = 0; mt < 4; mt++) {
                const int row = wm * 64 + mt * 16 + l16;
                a[mt] = *(const bf16x8*)&As[row * BK + (((quad + ub) ^ (row & 7)) << 3)];
            }
            #pragma unroll
            for (int nt = 0; nt < 2; nt++) {
                const int row = wn * 32 + nt * 16 + l16;
                b[nt] = *(const bf16x8*)&Bs[row * BK + (((quad + ub) ^ (row & 7)) << 3)];
            }
            #pragma unroll
            for (int mt = 0; mt < 4; mt++)
                #pragma unroll
                for (int nt = 0; nt < 2; nt++)
                    acc[mt][nt] = __builtin_amdgcn_mfma_f32_16x16x32_bf16(
                        a[mt], b[nt], acc[mt][nt], 0, 0, 0);
        }
    }

    #pragma unroll
    for (int mt = 0; mt < 4; mt++) {
        const int mb = m0 + wm * 64 + mt * 16 + quad * 4;
        #pragma unroll
        for (int nt = 0; nt < 2; nt++) {
            const int n = n0 + wn * 32 + nt * 16 + l16;
            #pragma unroll
            for (int r = 0; r < 4; r++)
                Ob[(size_t)(mb + r) * 256 + n] = acc[mt][nt][r];
        }
    }
}

// One launch: x -> bf16, Wq/Wk/Wv -> bf16, pack 3 fp32 biases.
__global__ __launch_bounds__(256)
void cvt_all(const float* __restrict__ x,
             const float* __restrict__ Wq, const float* __restrict__ Wk,
             const float* __restrict__ Wv,
             const float* __restrict__ bq, const float* __restrict__ bk,
             const float* __restrict__ bv,
             __bf16* __restrict__ xb, __bf16* __restrict__ Wqb,
             float* __restrict__ bpack)
{
    const int i = blockIdx.x * 256 + threadIdx.x;
    if (i < 1073152) {
        const float* s; __bf16* d; int off;
        if (i < 1048576)      { s = x;  d = xb;            off = i; }
        else if (i < 1056768) { s = Wq; d = Wqb;           off = i - 1048576; }
        else if (i < 1064960) { s = Wk; d = Wqb + 131072;  off = i - 1056768; }
        else                  { s = Wv; d = Wqb + 262144;  off = i - 1064960; }
        const float4* s4 = (const float4*)s;
        const float4 f0 = s4[off * 2], f1 = s4[off * 2 + 1];
        bf16x8 o;
        o[0] = (__bf16)f0.x; o[1] = (__bf16)f0.y; o[2] = (__bf16)f0.z; o[3] = (__bf16)f0.w;
        o[4] = (__bf16)f1.x; o[5] = (__bf16)f1.y; o[6] = (__bf16)f1.z; o[7] = (__bf16)f1.w;
        ((bf16x8*)d)[off] = o;
    } else if (i < 1073344) {
        const int j = i - 1073152;
        const int sel = j >> 6, jj = j & 63;
        const float* s = sel == 0 ? bq : (sel == 1 ? bk : bv);
        ((float4*)bpack)[j] = ((const float4*)s)[jj];
    }
}

// Srcp[n,m] = 1 / sum_b E[b,n,m]  (fp32, 4 MB). Streaming read of E (64MB).
__global__ __launch_bounds__(256)
void reduce_s(const __bf16* __restrict__ E, float* __restrict__ Srcp)
{
    const size_t p = (size_t)blockIdx.x * 256 + threadIdx.x;  // bf16x8 unit
    const bf16x8* E8 = (const bf16x8*)E;
    float s[8] = {0.f, 0.f, 0.f, 0.f, 0.f, 0.f, 0.f, 0.f};
    #pragma unroll
    for (int b = 0; b < 32; b++) {
        bf16x8 e = E8[(size_t)b * 131072 + p];
        #pragma unroll
        for (int j = 0; j < 8; j++) s[j] += (float)e[j];
    }
    f32x4 r0, r1;
    #pragma unroll
    for (int j = 0; j < 4; j++) r0[j] = __builtin_amdgcn_rcpf(s[j]);
    #pragma unroll
    for (int j = 0; j < 4; j++) r1[j] = __builtin_amdgcn_rcpf(s[j + 4]);
    ((f32x4*)Srcp)[p * 2]     = r0;
    ((f32x4*)Srcp)[p * 2 + 1] = r1;
}

extern "C" void kernel_launch(void* const* d_in, const int* in_sizes, int n_in,
                              void* d_out, int out_size, void* d_ws, size_t ws_size,
                              hipStream_t stream)
{
    const float* x  = (const float*)d_in[0];
    const float* Wq = (const float*)d_in[1];
    const float* bq = (const float*)d_in[2];
    const float* Wk = (const float*)d_in[3];
    const float* bk = (const float*)d_in[4];
    const float* Wv = (const float*)d_in[5];
    const float* bv = (const float*)d_in[6];
    float* out = (float*)d_out;

    // Workspace layout (bytes):
    //   [0,4M)     Srcp fp32 (1024x1024) -- reuses xb space (dead after proj)
    //   [0,16M)    xb   bf16 (32768x256)
    //   [16M,32M)  qb \
    //   [32M,48M)  kb  } stride 16M (8388608 elem)
    //   [48M,64M)  vT (32,256,1024)
    //   [64M,128M) E  bf16 (32,1024,1024)
    //   [128M,+768K) Wqb/Wkb/Wvb bf16 contiguous
    //   [+768K,+771K) bpack fp32[768]
    char* ws = (char*)d_ws;
    float*  Srcp  = (float*) (ws);
    __bf16* xb    = (__bf16*)(ws);
    __bf16* qkv   = (__bf16*)(ws + (16u << 20));
    __bf16* E     = (__bf16*)(ws + (64u << 20));
    __bf16* Wqb   = (__bf16*)(ws + (128u << 20));
    float*  bpack = (float*) (ws + (128u << 20) + (3u << 18));

    // 1) converts + bias pack
    cvt_all<<<4194, 256, 0, stream>>>(x, Wq, Wk, Wv, bq, bk, bv, xb, Wqb, bpack);

    // 2) q/k/v projections, one launch (z picks W/bias/output path)
    gemm_nt<4, 0><<<dim3(256, 2, 3), 256, 0, stream>>>(xb, Wqb, qkv, bpack,
                                                       256, 256, 256, 256,
                                                       0, 131072, 8388608);

    // 3) E[b] = exp(q[b] @ k[b]^T), XCD-sequential flat grid
    gemm_nt<2, 1><<<2048, 256, 0, stream>>>(qkv, qkv + 8388608, E, nullptr,
                                            256, 256, 1024, 256,
                                            262144, 262144, 1048576);

    // 4) Srcp = 1 / sum_b E  (xb dead; Srcp reuses its space)
    reduce_s<<<512, 256, 0, stream>>>(E, Srcp);

    // 5) out[b] = (E[b]*Srcp) @ vT[b]^T, normalize fused into A-staging,
    //    R5 PV geometry (grid 1024 = 4 blocks/CU)
    gemm_pv<<<1024, 256, 0, stream>>>(E, Srcp, qkv + 2 * 8388608, out);
}

// Round 11
// 231.402 us; speedup vs baseline: 1.8762x; 1.0981x over previous
//
#include <hip/hip_runtime.h>

typedef __bf16 bf16x8 __attribute__((ext_vector_type(8)));
typedef __bf16 bf16x4 __attribute__((ext_vector_type(4)));
typedef float  f32x4  __attribute__((ext_vector_type(4)));

#define BK 64

__device__ __forceinline__ void g2l16(const void* g, void* l) {
    __builtin_amdgcn_global_load_lds((const __attribute__((address_space(1))) void*)g,
                                     (__attribute__((address_space(3))) void*)l, 16, 0, 0);
}

__device__ __forceinline__ bf16x8 cvt8(const float* p) {
    const float4 f0 = *(const float4*)p, f1 = *(const float4*)(p + 4);
    bf16x8 o;
    o[0] = (__bf16)f0.x; o[1] = (__bf16)f0.y; o[2] = (__bf16)f0.z; o[3] = (__bf16)f0.w;
    o[4] = (__bf16)f1.x; o[5] = (__bf16)f1.y; o[6] = (__bf16)f1.z; o[7] = (__bf16)f1.w;
    return o;
}

// ---------------------------------------------------------------------------
// Projections with FUSED fp32->bf16 conversion in staging (kills the cvt
// launch + its gap). Tile 128x128, grid dim3(256,2,3), z picks q/k/v.
// Staging: VGPR roundtrip (2x float4 load -> pack bf16x8 -> swizzled
// ds_write_b128; bank pattern verified conflict-free in R4's A-path).
// Swizzle identical to gemm core: unit ^= row&7.
// Epilogue: R5-verified EPI4 (z<2 row-major q/k scalar stores; z==2
// transposed vT bf16x4 stores). Bias read directly from fp32 inputs.
// ---------------------------------------------------------------------------
__global__ __launch_bounds__(256)
void gemm_proj(const float* __restrict__ x,
               const float* __restrict__ Wq, const float* __restrict__ Wk,
               const float* __restrict__ Wv,
               const float* __restrict__ bq, const float* __restrict__ bk,
               const float* __restrict__ bv,
               __bf16* __restrict__ qkv, __bf16* __restrict__ vT)
{
    __shared__ __align__(16) __bf16 As[128 * 64];
    __shared__ __align__(16) __bf16 Bs[128 * 64];

    const int tid  = threadIdx.x;
    const int w    = tid >> 6;
    const int lane = tid & 63;
    const int quad = lane >> 4;
    const int l16  = lane & 15;
    const int wm   = w & 1;
    const int wn   = w >> 1;

    const int m0 = blockIdx.x * 128;     // x-row tile
    const int n0 = blockIdx.y * 128;     // out-dim tile
    const int z  = blockIdx.z;

    const float* W  = z == 0 ? Wq : (z == 1 ? Wk : Wv);
    const float* bb = z == 0 ? bq : (z == 1 ? bk : bv);

    // Staging: thread owns one row (tid>>1) and 32 cols half = (tid&1)*32.
    const int row  = tid >> 1;
    const int half = tid & 1;
    const float* Ag = x + (size_t)(m0 + row) * 256 + half * 32;
    const float* Bg = W + (size_t)(n0 + row) * 256 + half * 32;
    __bf16* Adst = As + row * 64;
    __bf16* Bdst = Bs + row * 64;

    f32x4 acc[4][4] = {};

    for (int k0 = 0; k0 < 256; k0 += BK) {
        __syncthreads();
        #pragma unroll
        for (int s = 0; s < 4; s++) {
            const int u = half * 4 + s;                  // 8-col unit index
            bf16x8 pa = cvt8(Ag + k0 + s * 8);
            bf16x8 pb = cvt8(Bg + k0 + s * 8);
            *(bf16x8*)(Adst + ((u ^ (row & 7)) << 3)) = pa;
            *(bf16x8*)(Bdst + ((u ^ (row & 7)) << 3)) = pb;
        }
        __syncthreads();

        #pragma unroll
        for (int kk = 0; kk < BK; kk += 32) {
            const int ub = kk >> 3;
            bf16x8 a[4], b[4];
            #pragma unroll
            for (int mt = 0; mt < 4; mt++) {
                const int rr = wm * 64 + mt * 16 + l16;
                a[mt] = *(const bf16x8*)&As[rr * 64 + (((quad + ub) ^ (rr & 7)) << 3)];
            }
            #pragma unroll
            for (int nt = 0; nt < 4; nt++) {
                const int rr = wn * 64 + nt * 16 + l16;
                b[nt] = *(const bf16x8*)&Bs[rr * 64 + (((quad + ub) ^ (rr & 7)) << 3)];
            }
            #pragma unroll
            for (int mt = 0; mt < 4; mt++)
                #pragma unroll
                for (int nt = 0; nt < 4; nt++)
                    acc[mt][nt] = __builtin_amdgcn_mfma_f32_16x16x32_bf16(
                        a[mt], b[nt], acc[mt][nt], 0, 0, 0);
        }
    }

    // Epilogue (R5-verified). C/D layout: row = quad*4 + reg, col = l16.
    #pragma unroll
    for (int mt = 0; mt < 4; mt++) {
        const int mb = m0 + wm * 64 + mt * 16 + quad * 4;
        #pragma unroll
        for (int nt = 0; nt < 4; nt++) {
            const int n = n0 + wn * 64 + nt * 16 + l16;
            const float bn = bb[n];
            if (z < 2) {
                __bf16* C = qkv + (size_t)z * 8388608;
                #pragma unroll
                for (int r = 0; r < 4; r++)
                    C[(size_t)(mb + r) * 256 + n] = (__bf16)(acc[mt][nt][r] + bn);
            } else {
                // vT[b][d=n][m]: batch stride 262144, d stride 1024
                const int bidx = mb >> 10, mloc = mb & 1023;
                bf16x4 pk;
                #pragma unroll
                for (int r = 0; r < 4; r++) pk[r] = (__bf16)(acc[mt][nt][r] + bn);
                *(bf16x4*)(vT + (size_t)bidx * 262144 + (size_t)n * 1024 + mloc) = pk;
            }
        }
    }
}

// ---------------------------------------------------------------------------
// Logits: E[z][qrow][krow] = exp(q.k). 128x128 tile, XCD-sequential flat
// grid (R5-verified: FETCH 74->12.5MB). Epilogue via LDS roundtrip with
// CONFLICT-AUDITED stride 132 bf16 (66 dwords): quad rows (stride 4) land
// at dword-banks {0,8,16,24} (4*66=264 === 8 mod 32); col-pairs 2-way (free,
// m136). Read back row-contiguous, 8x bf16x8 stores. (R3's failure was
// stride 144 = 72 dwords, 4*72 === 0 mod 32 -> 8-way conflicts.)
// ---------------------------------------------------------------------------
__global__ __launch_bounds__(256)
void gemm_logits(const __bf16* __restrict__ qb, const __bf16* __restrict__ kb,
                 __bf16* __restrict__ E)
{
    __shared__ __align__(16) char smem[33792];    // max(32768 main, 33792 epi)
    __bf16* As = (__bf16*)smem;
    __bf16* Bs = (__bf16*)(smem + 16384);

    const int tid  = threadIdx.x;
    const int w    = tid >> 6;
    const int lane = tid & 63;
    const int quad = lane >> 4;
    const int l16  = lane & 15;
    const int wm   = w & 1;
    const int wn   = w >> 1;

    const int id = blockIdx.x;
    const int x8 = id & 7, s = id >> 3;
    const int z  = x8 + ((s >> 6) << 3);
    const int t  = s & 63;
    const int m0 = (t & 7) * 128;      // q-row tile
    const int n0 = (t >> 3) * 128;     // k-row tile

    const __bf16* Ab = qb + (size_t)z * 262144;
    const __bf16* Bb = kb + (size_t)z * 262144;

    const int srow = (w << 3) + (lane >> 3);
    const int scol = ((lane & 7) ^ (lane >> 3)) << 3;
    char* ldsA = (char*)As + (size_t)w * 1024;
    char* ldsB = (char*)Bs + (size_t)w * 1024;
    const __bf16* Ag = Ab + (size_t)(m0 + srow) * 256 + scol;
    const __bf16* Bg = Bb + (size_t)(n0 + srow) * 256 + scol;

    f32x4 acc[4][4] = {};

    for (int k0 = 0; k0 < 256; k0 += BK) {
        __syncthreads();
        #pragma unroll
        for (int c = 0; c < 4; c++)
            g2l16(Ag + (size_t)(c * 32) * 256 + k0, ldsA + c * 4096);
        #pragma unroll
        for (int c = 0; c < 4; c++)
            g2l16(Bg + (size_t)(c * 32) * 256 + k0, ldsB + c * 4096);
        __syncthreads();

        #pragma unroll
        for (int kk = 0; kk < BK; kk += 32) {
            const int ub = kk >> 3;
            bf16x8 a[4], b[4];
            #pragma unroll
            for (int mt = 0; mt < 4; mt++) {
                const int rr = wm * 64 + mt * 16 + l16;
                a[mt] = *(const bf16x8*)&As[rr * 64 + (((quad + ub) ^ (rr & 7)) << 3)];
            }
            #pragma unroll
            for (int nt = 0; nt < 4; nt++) {
                const int rr = wn * 64 + nt * 16 + l16;
                b[nt] = *(const bf16x8*)&Bs[rr * 64 + (((quad + ub) ^ (rr & 7)) << 3)];
            }
            #pragma unroll
            for (int mt = 0; mt < 4; mt++)
                #pragma unroll
                for (int nt = 0; nt < 4; nt++)
                    acc[mt][nt] = __builtin_amdgcn_mfma_f32_16x16x32_bf16(
                        a[mt], b[nt], acc[mt][nt], 0, 0, 0);
        }
    }

    // Epilogue: exp -> LDS tile [128][132] bf16 -> vector global stores.
    __syncthreads();                      // As/Bs dead
    __bf16* eb = (__bf16*)smem;
    #pragma unroll
    for (int mt = 0; mt < 4; mt++) {
        const int rb = wm * 64 + mt * 16 + quad * 4;
        #pragma unroll
        for (int nt = 0; nt < 4; nt++) {
            const int c = wn * 64 + nt * 16 + l16;
            #pragma unroll
            for (int r = 0; r < 4; r++)
                eb[(rb + r) * 132 + c] = (__bf16)__expf(acc[mt][nt][r]);
        }
    }
    __syncthreads();
    const int row = tid >> 1, seg = tid & 1;
    __bf16* dst = E + (size_t)z * 1048576 + (size_t)(m0 + row) * 1024 + n0 + seg * 64;
    const __bf16* src = eb + row * 132 + seg * 64;
    #pragma unroll
    for (int u = 0; u < 8; u++)
        *(bf16x8*)(dst + u * 8) = *(const bf16x8*)(src + u * 8);
}

// ---------------------------------------------------------------------------
// Batch-axis softmax (R5-verified): S = sum_b E; E <- E/S, single pass,
// 32 slices cached in registers.
// ---------------------------------------------------------------------------
__global__ __launch_bounds__(256)
void softmax_norm(__bf16* __restrict__ E)
{
    const size_t p = (size_t)blockIdx.x * 256 + threadIdx.x;
    bf16x8* E8 = (bf16x8*)E;
    bf16x8 e[32];
    #pragma unroll
    for (int b = 0; b < 32; b++) e[b] = E8[(size_t)b * 131072 + p];
    float sm[8] = {0.f, 0.f, 0.f, 0.f, 0.f, 0.f, 0.f, 0.f};
    #pragma unroll
    for (int b = 0; b < 32; b++)
        #pragma unroll
        for (int j = 0; j < 8; j++) sm[j] += (float)e[b][j];
    float rs[8];
    #pragma unroll
    for (int j = 0; j < 8; j++) rs[j] = __builtin_amdgcn_rcpf(sm[j]);
    #pragma unroll
    for (int b = 0; b < 32; b++) {
        bf16x8 o = e[b];
        #pragma unroll
        for (int j = 0; j < 8; j++) o[j] = (__bf16)((float)o[j] * rs[j]);
        E8[(size_t)b * 131072 + p] = o;
    }
}

// ---------------------------------------------------------------------------
// PV (R5-verified): out[z][n][d] = attn[z] @ vT[z]^T. 128x64 tile, grid
// 1024 = 4 blocks/CU, XCD-sequential. Both operands on global_load_lds.
// ---------------------------------------------------------------------------
__global__ __launch_bounds__(256)
void gemm_pv(const __bf16* __restrict__ E, const __bf16* __restrict__ vT,
             float* __restrict__ out)
{
    __shared__ __align__(16) __bf16 As[128 * 64];   // 16 KB
    __shared__ __align__(16) __bf16 Bs[64 * 64];    //  8 KB

    const int tid  = threadIdx.x;
    const int w    = tid >> 6;
    const int lane = tid & 63;
    const int quad = lane >> 4;
    const int l16  = lane & 15;
    const int wm   = w & 1;        // 64-row half (n)
    const int wn   = w >> 1;       // 32-col half (d)

    const int id = blockIdx.x;
    const int x8 = id & 7, s = id >> 3;        // s: 0..127
    const int z  = x8 + ((s >> 5) << 3);
    const int t  = s & 31;
    const int m0 = (t & 7) * 128;              // n-row tile
    const int n0 = (t >> 3) * 64;              // d-col tile

    const __bf16* Eb = E  + (size_t)z * 1048576;
    const __bf16* Vb = vT + (size_t)z * 262144;
    float*        Ob = out + (size_t)z * 262144;

    const int srow = (w << 3) + (lane >> 3);
    const int scol = ((lane & 7) ^ (lane >> 3)) << 3;
    char* ldsA = (char*)As + (size_t)w * 1024;
    char* ldsB = (char*)Bs + (size_t)w * 1024;

    const __bf16* Ag = Eb + (size_t)(m0 + srow) * 1024 + scol;
    const __bf16* Bg = Vb + (size_t)(n0 + srow) * 1024 + scol;

    f32x4 acc[4][2] = {};

    for (int k0 = 0; k0 < 1024; k0 += BK) {
        __syncthreads();
        #pragma unroll
        for (int c = 0; c < 4; c++)
            g2l16(Ag + (size_t)(c * 32) * 1024 + k0, ldsA + c * 4096);
        #pragma unroll
        for (int c = 0; c < 2; c++)
            g2l16(Bg + (size_t)(c * 32) * 1024 + k0, ldsB + c * 4096);
        __syncthreads();

        #pragma unroll
        for (int kk = 0; kk < BK; kk += 32) {
            const int ub = kk >> 3;
            bf16x8 a[4], b[2];
            #pragma unroll
            for (int mt = 0; mt < 4; mt++) {
                const int rr = wm * 64 + mt * 16 + l16;
                a[mt] = *(const bf16x8*)&As[rr * 64 + (((quad + ub) ^ (rr & 7)) << 3)];
            }
            #pragma unroll
            for (int nt = 0; nt < 2; nt++) {
                const int rr = wn * 32 + nt * 16 + l16;
                b[nt] = *(const bf16x8*)&Bs[rr * 64 + (((quad + ub) ^ (rr & 7)) << 3)];
            }
            #pragma unroll
            for (int mt = 0; mt < 4; mt++)
                #pragma unroll
                for (int nt = 0; nt < 2; nt++)
                    acc[mt][nt] = __builtin_amdgcn_mfma_f32_16x16x32_bf16(
                        a[mt], b[nt], acc[mt][nt], 0, 0, 0);
        }
    }

    #pragma unroll
    for (int mt = 0; mt < 4; mt++) {
        const int mb = m0 + wm * 64 + mt * 16 + quad * 4;
        #pragma unroll
        for (int nt = 0; nt < 2; nt++) {
            const int n = n0 + wn * 32 + nt * 16 + l16;
            #pragma unroll
            for (int r = 0; r < 4; r++)
                Ob[(size_t)(mb + r) * 256 + n] = acc[mt][nt][r];
        }
    }
}

extern "C" void kernel_launch(void* const* d_in, const int* in_sizes, int n_in,
                              void* d_out, int out_size, void* d_ws, size_t ws_size,
                              hipStream_t stream)
{
    const float* x  = (const float*)d_in[0];
    const float* Wq = (const float*)d_in[1];
    const float* bq = (const float*)d_in[2];
    const float* Wk = (const float*)d_in[3];
    const float* bk = (const float*)d_in[4];
    const float* Wv = (const float*)d_in[5];
    const float* bv = (const float*)d_in[6];
    float* out = (float*)d_out;

    // Workspace layout (bytes):
    //   [16M,32M)  qb \
    //   [32M,48M)  kb  } stride 16M (8388608 elem)
    //   [48M,64M)  vT (32,256,1024)
    //   [64M,128M) E  bf16 (32,1024,1024)
    char* ws = (char*)d_ws;
    __bf16* qkv = (__bf16*)(ws + (16u << 20));
    __bf16* vT  = (__bf16*)(ws + (48u << 20));
    __bf16* E   = (__bf16*)(ws + (64u << 20));

    // 1) q/k/v projections with fused fp32->bf16 staging (no cvt launch)
    gemm_proj<<<dim3(256, 2, 3), 256, 0, stream>>>(x, Wq, Wk, Wv, bq, bk, bv,
                                                   qkv, vT);

    // 2) E[b] = exp(q[b] @ k[b]^T), XCD-sequential, LDS-roundtrip epilogue
    gemm_logits<<<2048, 256, 0, stream>>>(qkv, qkv + 8388608, E);

    // 3) batch-axis softmax normalize in place
    softmax_norm<<<512, 256, 0, stream>>>(E);

    // 4) out[b] = attn[b] @ vT[b]^T
    gemm_pv<<<1024, 256, 0, stream>>>(E, vT, out);
}